// Round 10
// baseline (1421.866 us; speedup 1.0000x reference)
//
#include <hip/hip_runtime.h>
#include <hip/hip_bf16.h>
#include <math.h>

typedef __bf16 bf16x8 __attribute__((ext_vector_type(8)));
typedef float  f32x4  __attribute__((ext_vector_type(4)));

#define GAS(p) ((const __attribute__((address_space(1))) void*)(p))
#define LAS(p) ((__attribute__((address_space(3))) void*)(p))

static constexpr int NE = 768;

// ---------------- embed: x = tok_emb[idx] + pos_emb, -> bf16 ----------------
__global__ __launch_bounds__(256) void k_embed(const int* __restrict__ idx,
    const float* __restrict__ tok, const float* __restrict__ pos,
    __hip_bfloat16* __restrict__ xb)
{
    int bt = blockIdx.x;            // 0..8191
    int t  = bt & 2047;
    int token = idx[bt];
    const float* te = tok + (size_t)token * NE;
    const float* pe = pos + (size_t)t * NE;
    __hip_bfloat16* o = xb + (size_t)bt * NE;
    for (int c = threadIdx.x; c < NE; c += 256)
        o[c] = __float2bfloat16(te[c] + pe[c]);
}

// ------------- transpose fp32 [R][C] -> bf16 [outRows][R] (zero-pad) -------------
__global__ __launch_bounds__(256) void k_transpose_f32_bf16(
    const float* __restrict__ in, __hip_bfloat16* __restrict__ out,
    int R, int C, int outRows)
{
    __shared__ float tile[32][33];
    int c0 = blockIdx.x * 32, r0 = blockIdx.y * 32;
    int tx = threadIdx.x & 31, ty = threadIdx.x >> 5;
    #pragma unroll
    for (int i = 0; i < 32; i += 8) {
        int r = r0 + ty + i, c = c0 + tx;
        tile[ty + i][tx] = (r < R && c < C) ? in[(size_t)r * C + c] : 0.f;
    }
    __syncthreads();
    #pragma unroll
    for (int i = 0; i < 32; i += 8) {
        int oc = c0 + ty + i, orr = r0 + tx;
        if (oc < outRows && orr < R)
            out[(size_t)oc * R + orr] = __float2bfloat16(tile[tx][ty + i]);
    }
}

// ------------- batched bf16 transpose: in [z][R][C] -> out [z][C][R] -------------
__global__ __launch_bounds__(256) void k_transpose_bf16(
    const __hip_bfloat16* __restrict__ in, __hip_bfloat16* __restrict__ out,
    int R, int C)
{
    __shared__ __hip_bfloat16 tile[32][33];
    size_t boff = (size_t)blockIdx.z * R * C;
    int c0 = blockIdx.x * 32, r0 = blockIdx.y * 32;
    int tx = threadIdx.x & 31, ty = threadIdx.x >> 5;
    #pragma unroll
    for (int i = 0; i < 32; i += 8)
        tile[ty + i][tx] = in[boff + (size_t)(r0 + ty + i) * C + (c0 + tx)];
    __syncthreads();
    #pragma unroll
    for (int i = 0; i < 32; i += 8)
        out[boff + (size_t)(c0 + ty + i) * R + (r0 + tx)] = tile[tx][ty + i];
}

__global__ __launch_bounds__(256) void k_pack_bias(const float* __restrict__ bq,
    const float* __restrict__ bk, const float* __restrict__ bv, float* __restrict__ o)
{
    int i = blockIdx.x * 256 + threadIdx.x;
    if (i < 768) o[i] = bq[i];
    else if (i < 1536) o[i] = bk[i - 768];
    else if (i < 2304) o[i] = bv[i - 1536];
}

// ---------------- m97-style 128x128 bf16 MFMA GEMM (qkv/att/PV) ----------------
template<int MODE>
__global__ __launch_bounds__(256) void k_gemm(
    const __hip_bfloat16* __restrict__ A, const __hip_bfloat16* __restrict__ Bt,
    int K, int lda, int ldb,
    size_t strideA, size_t strideB, size_t strideC,
    float* __restrict__ outf, int ldc, int ncols,
    const float* __restrict__ bias, float scale,
    __hip_bfloat16* __restrict__ oq, __hip_bfloat16* __restrict__ ok,
    __hip_bfloat16* __restrict__ ov)
{
    int bn = blockIdx.x, bm = blockIdx.y, bz = blockIdx.z;
    if constexpr (MODE == 2) bm = (int)gridDim.y - 1 - bm;   // longest-first dispatch
    if (MODE == 1 && bn > bm) return;   // fully masked causal tile
    __shared__ __align__(16) __hip_bfloat16 As[128 * 32];
    __shared__ __align__(16) __hip_bfloat16 Bs[128 * 32];
    const __hip_bfloat16* Ab = A  + bz * strideA + (size_t)bm * 128 * lda;
    const __hip_bfloat16* Bb = Bt + bz * strideB + (size_t)bn * 128 * ldb;
    int tid = threadIdx.x, w = tid >> 6, lane = tid & 63;
    int wr = w >> 1, wc = w & 1;
    f32x4 acc[4][4] = {};
    int sr = tid >> 2, sc = (tid & 3) * 8;
    int lr = lane & 15, lk = (lane >> 4) * 8;

    const int kend = (MODE == 2) ? (bm + 1) * 128 : K;   // causal K-truncation for PV

    for (int k0 = 0; k0 < kend; k0 += 32) {
        __syncthreads();
        #pragma unroll
        for (int i = 0; i < 2; ++i) {
            __builtin_amdgcn_global_load_lds(GAS(Ab + (size_t)(i * 64 + sr) * lda + k0 + sc),
                                             LAS((char*)As + i * 4096 + w * 1024), 16, 0, 0);
            __builtin_amdgcn_global_load_lds(GAS(Bb + (size_t)(i * 64 + sr) * ldb + k0 + sc),
                                             LAS((char*)Bs + i * 4096 + w * 1024), 16, 0, 0);
        }
        __syncthreads();
        bf16x8 af[4], bfv[4];
        #pragma unroll
        for (int mi = 0; mi < 4; ++mi)
            af[mi] = *(const bf16x8*)(As + (wr * 64 + mi * 16 + lr) * 32 + lk);
        #pragma unroll
        for (int ni = 0; ni < 4; ++ni)
            bfv[ni] = *(const bf16x8*)(Bs + (wc * 64 + ni * 16 + lr) * 32 + lk);
        #pragma unroll
        for (int mi = 0; mi < 4; ++mi)
            #pragma unroll
            for (int ni = 0; ni < 4; ++ni)
                acc[mi][ni] = __builtin_amdgcn_mfma_f32_16x16x32_bf16(af[mi], bfv[ni], acc[mi][ni], 0, 0, 0);
    }

    int r4 = (lane >> 4) * 4;
    #pragma unroll
    for (int mi = 0; mi < 4; ++mi) {
        #pragma unroll
        for (int ni = 0; ni < 4; ++ni) {
            #pragma unroll
            for (int r = 0; r < 4; ++r) {
                int row = bm * 128 + wr * 64 + mi * 16 + r4 + r;
                int col = bn * 128 + wc * 64 + ni * 16 + lr;
                float v = acc[mi][ni][r];
                if constexpr (MODE == 0) {
                    v += bias[col];
                    __hip_bfloat16 h = __float2bfloat16(v);
                    if (col < 768)       oq[(size_t)row * 768 + col]          = h;
                    else if (col < 1536) ok[(size_t)row * 768 + (col - 768)]  = h;
                    else                 ov[(size_t)row * 768 + (col - 1536)] = h;
                } else if constexpr (MODE == 1) {
                    outf[bz * strideC + (size_t)row * ldc + col] = v * scale;
                } else {
                    outf[bz * strideC + (size_t)row * ldc + col] = v;
                }
            }
        }
    }
}

// ================= persistent 256x256 head GEMM, BK=32, 4-slot LDS ring =================
// out[8192][V] = A[8192][768]*Bt[50432][768]^T + bias. 8 waves (2M x 4N).
// Each block: fixed bn, sweeps 4 bm-tiles = 96 continuous K-steps; ring never drains
// across tile boundaries (prologue paid once; B-panel L2-resident, re-read x4).
// Ring: 4 slots x (A 256x32 + B 256x32) = 128 KiB. Step u stages step u+3 into slot
// (u+3)&3 (= slot of u-1, freed at u-1's last barrier). One vmcnt(8) per step at
// phase B: forces only step-(u+1)'s 4 oldest loads (staged 4-6 phases earlier, deeper
// than HBM latency), keeps u+2/u+3 (8 loads) in flight. 2 phases/step (mh0/mh1),
// B-frags read once (phase A) and reused in phase B. Epilogue per bm-tile; its
// stores force-drain at the next tile's first vmcnt (accepted serial write).
__global__ __launch_bounds__(512, 2) void k_gemm_head(
    const __hip_bfloat16* __restrict__ A,   // [8192][768]
    const __hip_bfloat16* __restrict__ Bt,  // [50432][768]
    float* __restrict__ out, const float* __restrict__ bias, int ldc, int ncols)
{
    constexpr int K = 768, KT = K / 32;             // 24 K-steps per bm-tile
    constexpr int TILES = 4, NSTEP = KT * TILES;    // 96 continuous steps
    __shared__ __align__(16) __hip_bfloat16 As[4][256 * 32];
    __shared__ __align__(16) __hip_bfloat16 Bs[4][256 * 32];

    // bijective XCD remap of fast axis (R6-measured +6%)
    const int Nx = (int)gridDim.x;
    const int qq = Nx >> 3, rr = Nx & 7;
    const int xcd = (int)blockIdx.x & 7, xidx = (int)blockIdx.x >> 3;
    const int bn = (xcd < rr ? xcd * (qq + 1) : rr * (qq + 1) + (xcd - rr) * qq) + xidx;
    const int grp = blockIdx.y;                     // 8 groups x 4 bm-tiles
    const int tid = threadIdx.x;
    const int w = tid >> 6, lane = tid & 63;
    const int wr = w >> 2, wc = w & 3;              // wave tile: rows wr*128, cols wc*64
    const int lr = lane & 15, lu = lane >> 4;

    const __hip_bfloat16* Bp = Bt + (size_t)(bn * 256) * K;

    f32x4 acc[8][4] = {};
    bf16x8 bq[4];

    // swizzle for 32-wide rows (4x16B units): s(row) = (row ^ row>>2) & 3
    auto stageA = [&](int ws) {                     // step ws's A (256x32) -> slot ws&3
        int bm = grp * 4 + (ws / KT);
        int kt = ws - (ws / KT) * KT;
        const __hip_bfloat16* base = A + (size_t)(bm * 256) * K + kt * 32;
        #pragma unroll
        for (int l = 0; l < 2; ++l) {
            int v = l * 512 + tid;
            int row = v >> 2, uc = v & 3;
            int s = (row ^ (row >> 2)) & 3;
            __builtin_amdgcn_global_load_lds(GAS(base + (size_t)row * K + ((uc ^ s) << 3)),
                                             LAS(&As[ws & 3][v * 8]), 16, 0, 0);
        }
    };
    auto stageB = [&](int ws) {
        int kt = ws - (ws / KT) * KT;
        const __hip_bfloat16* base = Bp + kt * 32;
        #pragma unroll
        for (int l = 0; l < 2; ++l) {
            int v = l * 512 + tid;
            int row = v >> 2, uc = v & 3;
            int s = (row ^ (row >> 2)) & 3;
            __builtin_amdgcn_global_load_lds(GAS(base + (size_t)row * K + ((uc ^ s) << 3)),
                                             LAS(&Bs[ws & 3][v * 8]), 16, 0, 0);
        }
    };
    auto rdA = [&](int sl, int mh, int f) {
        int row = wr * 128 + mh * 64 + f * 16 + lr;
        int s = (row ^ (row >> 2)) & 3;
        return *(const bf16x8*)&As[sl][row * 32 + ((lu ^ s) << 3)];
    };
    auto rdB = [&](int sl, int n) {
        int row = wc * 64 + n * 16 + lr;
        int s = (row ^ (row >> 2)) & 3;
        return *(const bf16x8*)&Bs[sl][row * 32 + ((lu ^ s) << 3)];
    };

#define BAR() asm volatile("s_barrier" ::: "memory")

    // prologue: steps 0,1,2 (12 loads); vmcnt(8) retires step 0's 4
    stageA(0); stageB(0); stageA(1); stageB(1); stageA(2); stageB(2);
    asm volatile("s_waitcnt vmcnt(8)" ::: "memory");
    BAR();

    for (int u = 0; u < NSTEP; ++u) {
        const int sl = u & 3;
        // ---- phase A (mh0): read B once + A q-low; stage A(u+3) ----
        #pragma unroll
        for (int n = 0; n < 4; ++n) bq[n] = rdB(sl, n);
        {
            bf16x8 af[4];
            #pragma unroll
            for (int f = 0; f < 4; ++f) af[f] = rdA(sl, 0, f);
            if (u + 3 < NSTEP) stageA(u + 3);
            BAR();
            __builtin_amdgcn_s_setprio(1);
            #pragma unroll
            for (int n = 0; n < 4; ++n)
                #pragma unroll
                for (int f = 0; f < 4; ++f)
                    acc[f][n] = __builtin_amdgcn_mfma_f32_16x16x32_bf16(af[f], bq[n], acc[f][n], 0, 0, 0);
            __builtin_amdgcn_s_setprio(0);
            BAR();
        }
        // ---- phase B (mh1): A q-hi; stage B(u+3); single counted wait per step ----
        {
            bf16x8 af[4];
            #pragma unroll
            for (int f = 0; f < 4; ++f) af[f] = rdA(sl, 1, f);
            if (u + 3 < NSTEP) {
                stageB(u + 3);
                asm volatile("s_waitcnt vmcnt(8)" ::: "memory");   // gate u+1 (4-6 phases deep)
            } else if (u + 2 < NSTEP) {
                asm volatile("s_waitcnt vmcnt(4)" ::: "memory");
            } else if (u + 1 < NSTEP) {
                asm volatile("s_waitcnt vmcnt(0)" ::: "memory");
            }
            BAR();
            __builtin_amdgcn_s_setprio(1);
            #pragma unroll
            for (int n = 0; n < 4; ++n)
                #pragma unroll
                for (int f = 0; f < 4; ++f)
                    acc[4 + f][n] = __builtin_amdgcn_mfma_f32_16x16x32_bf16(af[f], bq[n], acc[4 + f][n], 0, 0, 0);
            __builtin_amdgcn_s_setprio(0);
            BAR();
        }
        // ---- per-bm-tile epilogue: write + re-zero acc ----
        if (((u + 1) % KT) == 0) {
            const int bm = grp * 4 + (u / KT);
            const int r4 = lu * 4;
            #pragma unroll
            for (int m = 0; m < 8; ++m) {
                #pragma unroll
                for (int n = 0; n < 4; ++n) {
                    int col = bn * 256 + wc * 64 + n * 16 + lr;
                    if (col < ncols) {
                        float bv_ = bias[col];
                        #pragma unroll
                        for (int r = 0; r < 4; ++r) {
                            int row = bm * 256 + wr * 128 + m * 16 + r4 + r;
                            out[(size_t)row * ldc + col] = acc[m][n][r] + bv_;
                        }
                    }
                    #pragma unroll
                    for (int r = 0; r < 4; ++r) acc[m][n][r] = 0.f;
                }
            }
        }
    }
#undef BAR
}

// ---------------- causal softmax: float4 loads, __expf, zero-fill to 128-boundary ----------------
__global__ __launch_bounds__(256) void k_softmax(const float* __restrict__ att,
    __hip_bfloat16* __restrict__ P, int T)
{
    int t = blockIdx.x, b = blockIdx.y;
    const float* row = att + ((size_t)b * T + t) * T;
    __hip_bfloat16* prow = P + ((size_t)b * T + t) * T;
    const int n = t + 1;
    const int nz = ((t >> 7) + 1) << 7;     // PV (truncated) reads only cols < nz
    __shared__ float red[256];
    float4 v[2];
    float mx = -1e30f;
    #pragma unroll
    for (int j = 0; j < 2; ++j) {
        int e = (threadIdx.x + j * 256) * 4;
        v[j] = *(const float4*)(row + e);
        #pragma unroll
        for (int k = 0; k < 4; ++k)
            if (e + k < n) mx = fmaxf(mx, ((const float*)&v[j])[k]);
    }
    red[threadIdx.x] = mx; __syncthreads();
    for (int o = 128; o > 0; o >>= 1) {
        if (threadIdx.x < o) red[threadIdx.x] = fmaxf(red[threadIdx.x], red[threadIdx.x + o]);
        __syncthreads();
    }
    mx = red[0]; __syncthreads();
    float ev[8];
    float sum = 0.f;
    #pragma unroll
    for (int j = 0; j < 2; ++j) {
        int e = (threadIdx.x + j * 256) * 4;
        #pragma unroll
        for (int k = 0; k < 4; ++k) {
            float x = ((const float*)&v[j])[k];
            float ex = (e + k < n) ? __expf(x - mx) : 0.f;
            ev[j * 4 + k] = ex;
            sum += ex;
        }
    }
    red[threadIdx.x] = sum; __syncthreads();
    for (int o = 128; o > 0; o >>= 1) {
        if (threadIdx.x < o) red[threadIdx.x] += red[threadIdx.x + o];
        __syncthreads();
    }
    float inv = 1.f / red[0];
    #pragma unroll
    for (int j = 0; j < 2; ++j) {
        int e = (threadIdx.x + j * 256) * 4;
        #pragma unroll
        for (int k = 0; k < 4; ++k)
            if (e + k < nz) prow[e + k] = __float2bfloat16(ev[j * 4 + k] * inv);
    }
}

// ---------------- LayerNorm (eps 1e-5) fp32 -> bf16 ----------------
__global__ __launch_bounds__(256) void k_layernorm(const float* __restrict__ y,
    const float* __restrict__ g, const float* __restrict__ b,
    __hip_bfloat16* __restrict__ yn)
{
    int row = blockIdx.x;
    const float* yr = y + (size_t)row * NE;
    float s = 0.f, s2 = 0.f;
    for (int c = threadIdx.x; c < NE; c += 256) { float v = yr[c]; s += v; s2 += v * v; }
    __shared__ float r1[256], r2[256];
    r1[threadIdx.x] = s; r2[threadIdx.x] = s2; __syncthreads();
    for (int o = 128; o > 0; o >>= 1) {
        if (threadIdx.x < o) { r1[threadIdx.x] += r1[threadIdx.x + o]; r2[threadIdx.x] += r2[threadIdx.x + o]; }
        __syncthreads();
    }
    float mu = r1[0] / NE;
    float var = r2[0] / NE - mu * mu;
    float rs = rsqrtf(var + 1e-5f);
    __hip_bfloat16* o = yn + (size_t)row * NE;
    for (int c = threadIdx.x; c < NE; c += 256)
        o[c] = __float2bfloat16((yr[c] - mu) * rs * g[c] + b[c]);
}

extern "C" void kernel_launch(void* const* d_in, const int* in_sizes, int n_in,
                              void* d_out, int out_size, void* d_ws, size_t ws_size,
                              hipStream_t stream)
{
    const int*   idx  = (const int*)  d_in[0];
    const float* tok  = (const float*)d_in[1];
    const float* pos  = (const float*)d_in[2];
    const float* Wq   = (const float*)d_in[3];
    const float* bq   = (const float*)d_in[4];
    const float* Wk   = (const float*)d_in[5];
    const float* bk   = (const float*)d_in[6];
    const float* Wv   = (const float*)d_in[7];
    const float* bv   = (const float*)d_in[8];
    const float* ln_g = (const float*)d_in[9];
    const float* ln_b = (const float*)d_in[10];
    const float* Wh   = (const float*)d_in[11];
    const float* bh   = (const float*)d_in[12];
    float* out = (float*)d_out;

    const int B = 4, T = 2048, C = 768, V = 50257, Vp = 50432;  // Vp = 197*256

    char* p = (char*)d_ws;
    auto take = [&](size_t bytes) { char* r = p; p += (bytes + 255) & ~(size_t)255; return r; };
    __hip_bfloat16* xb    = (__hip_bfloat16*)take((size_t)B * T * C * 2);
    __hip_bfloat16* wqkvT = (__hip_bfloat16*)take((size_t)3 * C * C * 2);
    float*          bqkv  = (float*)take((size_t)3 * C * 4);
    __hip_bfloat16* qb    = (__hip_bfloat16*)take((size_t)B * T * C * 2);
    __hip_bfloat16* kb    = (__hip_bfloat16*)take((size_t)B * T * C * 2);
    __hip_bfloat16* vb    = (__hip_bfloat16*)take((size_t)B * T * C * 2);
    __hip_bfloat16* vT    = (__hip_bfloat16*)take((size_t)B * T * C * 2);
    float*          att   = (float*)take((size_t)B * T * T * 4);
    __hip_bfloat16* P     = (__hip_bfloat16*)take((size_t)B * T * T * 2);
    float*          y     = (float*)take((size_t)B * T * C * 4);
    __hip_bfloat16* yn    = (__hip_bfloat16*)take((size_t)B * T * C * 2);
    // Wh^T (77.4 MB, Vp rows) reuses the att+P region (100.6 MB) — dead once y exists.
    __hip_bfloat16* whT   = (__hip_bfloat16*)att;

    float scale = 1.0f / sqrtf((float)C);

    k_embed<<<dim3(B * T), 256, 0, stream>>>(idx, tok, pos, xb);
    k_transpose_f32_bf16<<<dim3(24, 24), 256, 0, stream>>>(Wq, wqkvT,             C, C, C);
    k_transpose_f32_bf16<<<dim3(24, 24), 256, 0, stream>>>(Wk, wqkvT + C * C,     C, C, C);
    k_transpose_f32_bf16<<<dim3(24, 24), 256, 0, stream>>>(Wv, wqkvT + 2 * C * C, C, C, C);
    k_pack_bias<<<dim3(9), 256, 0, stream>>>(bq, bk, bv, bqkv);

    // qkv: [8192,768] x [2304,768]^T
    k_gemm<0><<<dim3(18, 64, 1), 256, 0, stream>>>(xb, wqkvT, C, C, C, 0, 0, 0,
        nullptr, 0, 0, bqkv, 1.f, qb, kb, vb);

    k_transpose_bf16<<<dim3(24, 64, B), 256, 0, stream>>>(vb, vT, T, C);

    // att = q k^T / sqrt(C): per batch [2048,768] x [2048,768]^T (causal block skip)
    k_gemm<1><<<dim3(16, 16, B), 256, 0, stream>>>(qb, kb, C, C, C,
        (size_t)T * C, (size_t)T * C, (size_t)T * T, att, T, 0, nullptr, scale,
        nullptr, nullptr, nullptr);

    k_softmax<<<dim3(T, B), 256, 0, stream>>>(att, P, T);

    // y = P v: per batch [2048,2048] x [768,2048]^T, K truncated causally, longest-first
    k_gemm<2><<<dim3(6, 16, B), 256, 0, stream>>>(P, vT, T, T, T,
        (size_t)T * T, (size_t)C * T, (size_t)T * C, y, C, 0, nullptr, 1.f,
        nullptr, nullptr, nullptr);

    // Wh^T after PV so it can overwrite att/P scratch
    k_transpose_f32_bf16<<<dim3(Vp / 32, 24), 256, 0, stream>>>(Wh, whT, C, V, Vp);

    k_layernorm<<<dim3(B * T), 256, 0, stream>>>(y, ln_g, ln_b, yn);

    // logits: [8192,768] x [50432,768]^T -> fp32 d_out; persistent 4-slot-ring kernel
    k_gemm_head<<<dim3(197, 8), 512, 0, stream>>>(yn, whT, out, bh, V, V);
}

// Round 11
// 1360.541 us; speedup vs baseline: 1.0451x; 1.0451x over previous
//
#include <hip/hip_runtime.h>
#include <hip/hip_bf16.h>
#include <math.h>

typedef __bf16 bf16x8 __attribute__((ext_vector_type(8)));
typedef float  f32x4  __attribute__((ext_vector_type(4)));

#define GAS(p) ((const __attribute__((address_space(1))) void*)(p))
#define LAS(p) ((__attribute__((address_space(3))) void*)(p))

static constexpr int NE = 768;

// ---------------- embed: x = tok_emb[idx] + pos_emb, -> bf16 ----------------
__global__ __launch_bounds__(256) void k_embed(const int* __restrict__ idx,
    const float* __restrict__ tok, const float* __restrict__ pos,
    __hip_bfloat16* __restrict__ xb)
{
    int bt = blockIdx.x;            // 0..8191
    int t  = bt & 2047;
    int token = idx[bt];
    const float* te = tok + (size_t)token * NE;
    const float* pe = pos + (size_t)t * NE;
    __hip_bfloat16* o = xb + (size_t)bt * NE;
    for (int c = threadIdx.x; c < NE; c += 256)
        o[c] = __float2bfloat16(te[c] + pe[c]);
}

// ------------- transpose fp32 [R][C] -> bf16 [outRows][R] (zero-pad) -------------
__global__ __launch_bounds__(256) void k_transpose_f32_bf16(
    const float* __restrict__ in, __hip_bfloat16* __restrict__ out,
    int R, int C, int outRows)
{
    __shared__ float tile[32][33];
    int c0 = blockIdx.x * 32, r0 = blockIdx.y * 32;
    int tx = threadIdx.x & 31, ty = threadIdx.x >> 5;
    #pragma unroll
    for (int i = 0; i < 32; i += 8) {
        int r = r0 + ty + i, c = c0 + tx;
        tile[ty + i][tx] = (r < R && c < C) ? in[(size_t)r * C + c] : 0.f;
    }
    __syncthreads();
    #pragma unroll
    for (int i = 0; i < 32; i += 8) {
        int oc = c0 + ty + i, orr = r0 + tx;
        if (oc < outRows && orr < R)
            out[(size_t)oc * R + orr] = __float2bfloat16(tile[tx][ty + i]);
    }
}

// ------------- batched bf16 transpose: in [z][R][C] -> out [z][C][R] -------------
__global__ __launch_bounds__(256) void k_transpose_bf16(
    const __hip_bfloat16* __restrict__ in, __hip_bfloat16* __restrict__ out,
    int R, int C)
{
    __shared__ __hip_bfloat16 tile[32][33];
    size_t boff = (size_t)blockIdx.z * R * C;
    int c0 = blockIdx.x * 32, r0 = blockIdx.y * 32;
    int tx = threadIdx.x & 31, ty = threadIdx.x >> 5;
    #pragma unroll
    for (int i = 0; i < 32; i += 8)
        tile[ty + i][tx] = in[boff + (size_t)(r0 + ty + i) * C + (c0 + tx)];
    __syncthreads();
    #pragma unroll
    for (int i = 0; i < 32; i += 8)
        out[boff + (size_t)(c0 + ty + i) * R + (r0 + tx)] = tile[tx][ty + i];
}

__global__ __launch_bounds__(256) void k_pack_bias(const float* __restrict__ bq,
    const float* __restrict__ bk, const float* __restrict__ bv, float* __restrict__ o)
{
    int i = blockIdx.x * 256 + threadIdx.x;
    if (i < 768) o[i] = bq[i];
    else if (i < 1536) o[i] = bk[i - 768];
    else if (i < 2304) o[i] = bv[i - 1536];
}

// ---------------- m97-style 128x128 bf16 MFMA GEMM (qkv/att/PV) ----------------
template<int MODE>
__global__ __launch_bounds__(256) void k_gemm(
    const __hip_bfloat16* __restrict__ A, const __hip_bfloat16* __restrict__ Bt,
    int K, int lda, int ldb,
    size_t strideA, size_t strideB, size_t strideC,
    float* __restrict__ outf, int ldc, int ncols,
    const float* __restrict__ bias, float scale,
    __hip_bfloat16* __restrict__ oq, __hip_bfloat16* __restrict__ ok,
    __hip_bfloat16* __restrict__ ov)
{
    int bn = blockIdx.x, bm = blockIdx.y, bz = blockIdx.z;
    if constexpr (MODE == 2) bm = (int)gridDim.y - 1 - bm;   // longest-first dispatch
    if (MODE == 1 && bn > bm) return;   // fully masked causal tile
    __shared__ __align__(16) __hip_bfloat16 As[128 * 32];
    __shared__ __align__(16) __hip_bfloat16 Bs[128 * 32];
    const __hip_bfloat16* Ab = A  + bz * strideA + (size_t)bm * 128 * lda;
    const __hip_bfloat16* Bb = Bt + bz * strideB + (size_t)bn * 128 * ldb;
    int tid = threadIdx.x, w = tid >> 6, lane = tid & 63;
    int wr = w >> 1, wc = w & 1;
    f32x4 acc[4][4] = {};
    int sr = tid >> 2, sc = (tid & 3) * 8;
    int lr = lane & 15, lk = (lane >> 4) * 8;

    const int kend = (MODE == 2) ? (bm + 1) * 128 : K;   // causal K-truncation for PV

    for (int k0 = 0; k0 < kend; k0 += 32) {
        __syncthreads();
        #pragma unroll
        for (int i = 0; i < 2; ++i) {
            __builtin_amdgcn_global_load_lds(GAS(Ab + (size_t)(i * 64 + sr) * lda + k0 + sc),
                                             LAS((char*)As + i * 4096 + w * 1024), 16, 0, 0);
            __builtin_amdgcn_global_load_lds(GAS(Bb + (size_t)(i * 64 + sr) * ldb + k0 + sc),
                                             LAS((char*)Bs + i * 4096 + w * 1024), 16, 0, 0);
        }
        __syncthreads();
        bf16x8 af[4], bfv[4];
        #pragma unroll
        for (int mi = 0; mi < 4; ++mi)
            af[mi] = *(const bf16x8*)(As + (wr * 64 + mi * 16 + lr) * 32 + lk);
        #pragma unroll
        for (int ni = 0; ni < 4; ++ni)
            bfv[ni] = *(const bf16x8*)(Bs + (wc * 64 + ni * 16 + lr) * 32 + lk);
        #pragma unroll
        for (int mi = 0; mi < 4; ++mi)
            #pragma unroll
            for (int ni = 0; ni < 4; ++ni)
                acc[mi][ni] = __builtin_amdgcn_mfma_f32_16x16x32_bf16(af[mi], bfv[ni], acc[mi][ni], 0, 0, 0);
    }

    int r4 = (lane >> 4) * 4;
    #pragma unroll
    for (int mi = 0; mi < 4; ++mi) {
        #pragma unroll
        for (int ni = 0; ni < 4; ++ni) {
            #pragma unroll
            for (int r = 0; r < 4; ++r) {
                int row = bm * 128 + wr * 64 + mi * 16 + r4 + r;
                int col = bn * 128 + wc * 64 + ni * 16 + lr;
                float v = acc[mi][ni][r];
                if constexpr (MODE == 0) {
                    v += bias[col];
                    __hip_bfloat16 h = __float2bfloat16(v);
                    if (col < 768)       oq[(size_t)row * 768 + col]          = h;
                    else if (col < 1536) ok[(size_t)row * 768 + (col - 768)]  = h;
                    else                 ov[(size_t)row * 768 + (col - 1536)] = h;
                } else if constexpr (MODE == 1) {
                    outf[bz * strideC + (size_t)row * ldc + col] = v * scale;
                } else {
                    outf[bz * strideC + (size_t)row * ldc + col] = v;
                }
            }
        }
    }
}

// ================= 256x128 head GEMM, BK=32, double-buffer, 2 blocks/CU =================
// out[8192][V] = A[8192][768]*Bt[50432][768]^T + bias. 8 waves (4M x 2N), each wave
// a 64x64 sub-tile (acc = 4x4 f32x4 = 64 VGPR). LDS = (A 256x32 + B 128x32) x 2buf
// = 48 KiB; __launch_bounds__(512,4) caps VGPR at 128 -> 2 blocks/CU. The co-resident
// block hides the per-step vmcnt/barrier drain (m97 mechanism — the measured 36%
// structure — instead of the 1-block/CU phase choreography stuck at 22-26%).
// Loop = T3-minimum 2-phase: stage(next, other buf) -> ds_read(cur) -> MFMA ->
// __syncthreads() (compiler emits the vmcnt/lgkm drain; dbuf keeps it off the
// critical path of THIS block, overlap covers the rest).
// Swizzle (32-wide rows, 4x16B units): unit ^= (row>>1)&3 — lanes 0-7 of a b128
// read hit 8 distinct bank-quads (hand-verified); same involution on source+read.
// Grid bm-fast (x=32): B-panel (197KB) shared by 32 co-resident bm-blocks;
// FETCH stays ~sub-GB (R7-validated grid mechanism).
__global__ __launch_bounds__(512, 4) void k_gemm_head(
    const __hip_bfloat16* __restrict__ A,   // [8192][768]
    const __hip_bfloat16* __restrict__ Bt,  // [50432][768]
    float* __restrict__ out, const float* __restrict__ bias, int ldc, int ncols)
{
    constexpr int K = 768, NT = K / 32;     // 24 K-steps
    __shared__ __align__(16) __hip_bfloat16 As[2][256 * 32];
    __shared__ __align__(16) __hip_bfloat16 Bs[2][128 * 32];

    const int bm = blockIdx.x, bn = blockIdx.y;   // bm fastest -> B-panel reuse
    const int tid = threadIdx.x;
    const int w = tid >> 6, lane = tid & 63;
    const int wr = w >> 1, wc = w & 1;            // wave tile: rows wr*64, cols wc*64
    const int lr = lane & 15, lu = lane >> 4;     // fragment lane mapping (unit = lu)

    const __hip_bfloat16* Ap = A  + (size_t)(bm * 256) * K;
    const __hip_bfloat16* Bp = Bt + (size_t)(bn * 128) * K;

    f32x4 acc[4][4] = {};

    auto stage = [&](int kt, int pb) {            // A 2 insts + B 1 inst per thread
        #pragma unroll
        for (int l = 0; l < 2; ++l) {
            int v = l * 512 + tid;
            int row = v >> 2, uc = v & 3;
            int s = (row >> 1) & 3;
            __builtin_amdgcn_global_load_lds(GAS(Ap + (size_t)row * K + kt * 32 + ((uc ^ s) << 3)),
                                             LAS(&As[pb][v * 8]), 16, 0, 0);
        }
        {
            int v = tid;
            int row = v >> 2, uc = v & 3;
            int s = (row >> 1) & 3;
            __builtin_amdgcn_global_load_lds(GAS(Bp + (size_t)row * K + kt * 32 + ((uc ^ s) << 3)),
                                             LAS(&Bs[pb][v * 8]), 16, 0, 0);
        }
    };
    auto rdA = [&](int pb, int m) {
        int row = wr * 64 + m * 16 + lr;
        int s = (row >> 1) & 3;
        return *(const bf16x8*)&As[pb][row * 32 + ((lu ^ s) << 3)];
    };
    auto rdB = [&](int pb, int n) {
        int row = wc * 64 + n * 16 + lr;
        int s = (row >> 1) & 3;
        return *(const bf16x8*)&Bs[pb][row * 32 + ((lu ^ s) << 3)];
    };

    stage(0, 0);
    __syncthreads();

    for (int kt = 0; kt < NT; ++kt) {
        const int p = kt & 1;
        if (kt + 1 < NT) stage(kt + 1, p ^ 1);
        bf16x8 bfv[4];
        #pragma unroll
        for (int n = 0; n < 4; ++n) bfv[n] = rdB(p, n);
        #pragma unroll
        for (int m = 0; m < 4; ++m) {
            bf16x8 a = rdA(p, m);
            #pragma unroll
            for (int n = 0; n < 4; ++n)
                acc[m][n] = __builtin_amdgcn_mfma_f32_16x16x32_bf16(a, bfv[n], acc[m][n], 0, 0, 0);
        }
        __syncthreads();   // drains vmcnt (next-tile staging) + lgkm; overlapped by co-resident block
    }

    // epilogue: C-write with bias, col-bounded
    const int r4 = lu * 4;
    #pragma unroll
    for (int m = 0; m < 4; ++m) {
        #pragma unroll
        for (int n = 0; n < 4; ++n) {
            int col = bn * 128 + wc * 64 + n * 16 + lr;
            if (col < ncols) {
                float bv_ = bias[col];
                #pragma unroll
                for (int r = 0; r < 4; ++r) {
                    int row = bm * 256 + wr * 64 + m * 16 + r4 + r;
                    out[(size_t)row * ldc + col] = acc[m][n][r] + bv_;
                }
            }
        }
    }
}

// ---------------- causal softmax: float4 loads, __expf, zero-fill to 128-boundary ----------------
__global__ __launch_bounds__(256) void k_softmax(const float* __restrict__ att,
    __hip_bfloat16* __restrict__ P, int T)
{
    int t = blockIdx.x, b = blockIdx.y;
    const float* row = att + ((size_t)b * T + t) * T;
    __hip_bfloat16* prow = P + ((size_t)b * T + t) * T;
    const int n = t + 1;
    const int nz = ((t >> 7) + 1) << 7;     // PV (truncated) reads only cols < nz
    __shared__ float red[256];
    float4 v[2];
    float mx = -1e30f;
    #pragma unroll
    for (int j = 0; j < 2; ++j) {
        int e = (threadIdx.x + j * 256) * 4;
        v[j] = *(const float4*)(row + e);
        #pragma unroll
        for (int k = 0; k < 4; ++k)
            if (e + k < n) mx = fmaxf(mx, ((const float*)&v[j])[k]);
    }
    red[threadIdx.x] = mx; __syncthreads();
    for (int o = 128; o > 0; o >>= 1) {
        if (threadIdx.x < o) red[threadIdx.x] = fmaxf(red[threadIdx.x], red[threadIdx.x + o]);
        __syncthreads();
    }
    mx = red[0]; __syncthreads();
    float ev[8];
    float sum = 0.f;
    #pragma unroll
    for (int j = 0; j < 2; ++j) {
        int e = (threadIdx.x + j * 256) * 4;
        #pragma unroll
        for (int k = 0; k < 4; ++k) {
            float x = ((const float*)&v[j])[k];
            float ex = (e + k < n) ? __expf(x - mx) : 0.f;
            ev[j * 4 + k] = ex;
            sum += ex;
        }
    }
    red[threadIdx.x] = sum; __syncthreads();
    for (int o = 128; o > 0; o >>= 1) {
        if (threadIdx.x < o) red[threadIdx.x] += red[threadIdx.x + o];
        __syncthreads();
    }
    float inv = 1.f / red[0];
    #pragma unroll
    for (int j = 0; j < 2; ++j) {
        int e = (threadIdx.x + j * 256) * 4;
        #pragma unroll
        for (int k = 0; k < 4; ++k)
            if (e + k < nz) prow[e + k] = __float2bfloat16(ev[j * 4 + k] * inv);
    }
}

// ---------------- LayerNorm (eps 1e-5) fp32 -> bf16 ----------------
__global__ __launch_bounds__(256) void k_layernorm(const float* __restrict__ y,
    const float* __restrict__ g, const float* __restrict__ b,
    __hip_bfloat16* __restrict__ yn)
{
    int row = blockIdx.x;
    const float* yr = y + (size_t)row * NE;
    float s = 0.f, s2 = 0.f;
    for (int c = threadIdx.x; c < NE; c += 256) { float v = yr[c]; s += v; s2 += v * v; }
    __shared__ float r1[256], r2[256];
    r1[threadIdx.x] = s; r2[threadIdx.x] = s2; __syncthreads();
    for (int o = 128; o > 0; o >>= 1) {
        if (threadIdx.x < o) { r1[threadIdx.x] += r1[threadIdx.x + o]; r2[threadIdx.x] += r2[threadIdx.x + o]; }
        __syncthreads();
    }
    float mu = r1[0] / NE;
    float var = r2[0] / NE - mu * mu;
    float rs = rsqrtf(var + 1e-5f);
    __hip_bfloat16* o = yn + (size_t)row * NE;
    for (int c = threadIdx.x; c < NE; c += 256)
        o[c] = __float2bfloat16((yr[c] - mu) * rs * g[c] + b[c]);
}

extern "C" void kernel_launch(void* const* d_in, const int* in_sizes, int n_in,
                              void* d_out, int out_size, void* d_ws, size_t ws_size,
                              hipStream_t stream)
{
    const int*   idx  = (const int*)  d_in[0];
    const float* tok  = (const float*)d_in[1];
    const float* pos  = (const float*)d_in[2];
    const float* Wq   = (const float*)d_in[3];
    const float* bq   = (const float*)d_in[4];
    const float* Wk   = (const float*)d_in[5];
    const float* bk   = (const float*)d_in[6];
    const float* Wv   = (const float*)d_in[7];
    const float* bv   = (const float*)d_in[8];
    const float* ln_g = (const float*)d_in[9];
    const float* ln_b = (const float*)d_in[10];
    const float* Wh   = (const float*)d_in[11];
    const float* bh   = (const float*)d_in[12];
    float* out = (float*)d_out;

    const int B = 4, T = 2048, C = 768, V = 50257, Vp = 50432;  // Vp = 394*128

    char* p = (char*)d_ws;
    auto take = [&](size_t bytes) { char* r = p; p += (bytes + 255) & ~(size_t)255; return r; };
    __hip_bfloat16* xb    = (__hip_bfloat16*)take((size_t)B * T * C * 2);
    __hip_bfloat16* wqkvT = (__hip_bfloat16*)take((size_t)3 * C * C * 2);
    float*          bqkv  = (float*)take((size_t)3 * C * 4);
    __hip_bfloat16* qb    = (__hip_bfloat16*)take((size_t)B * T * C * 2);
    __hip_bfloat16* kb    = (__hip_bfloat16*)take((size_t)B * T * C * 2);
    __hip_bfloat16* vb    = (__hip_bfloat16*)take((size_t)B * T * C * 2);
    __hip_bfloat16* vT    = (__hip_bfloat16*)take((size_t)B * T * C * 2);
    float*          att   = (float*)take((size_t)B * T * T * 4);
    __hip_bfloat16* P     = (__hip_bfloat16*)take((size_t)B * T * T * 2);
    float*          y     = (float*)take((size_t)B * T * C * 4);
    __hip_bfloat16* yn    = (__hip_bfloat16*)take((size_t)B * T * C * 2);
    // Wh^T (77.4 MB, Vp rows) reuses the att+P region (100.6 MB) — dead once y exists.
    __hip_bfloat16* whT   = (__hip_bfloat16*)att;

    float scale = 1.0f / sqrtf((float)C);

    k_embed<<<dim3(B * T), 256, 0, stream>>>(idx, tok, pos, xb);
    k_transpose_f32_bf16<<<dim3(24, 24), 256, 0, stream>>>(Wq, wqkvT,             C, C, C);
    k_transpose_f32_bf16<<<dim3(24, 24), 256, 0, stream>>>(Wk, wqkvT + C * C,     C, C, C);
    k_transpose_f32_bf16<<<dim3(24, 24), 256, 0, stream>>>(Wv, wqkvT + 2 * C * C, C, C, C);
    k_pack_bias<<<dim3(9), 256, 0, stream>>>(bq, bk, bv, bqkv);

    // qkv: [8192,768] x [2304,768]^T
    k_gemm<0><<<dim3(18, 64, 1), 256, 0, stream>>>(xb, wqkvT, C, C, C, 0, 0, 0,
        nullptr, 0, 0, bqkv, 1.f, qb, kb, vb);

    k_transpose_bf16<<<dim3(24, 64, B), 256, 0, stream>>>(vb, vT, T, C);

    // att = q k^T / sqrt(C): per batch [2048,768] x [2048,768]^T (causal block skip)
    k_gemm<1><<<dim3(16, 16, B), 256, 0, stream>>>(qb, kb, C, C, C,
        (size_t)T * C, (size_t)T * C, (size_t)T * T, att, T, 0, nullptr, scale,
        nullptr, nullptr, nullptr);

    k_softmax<<<dim3(T, B), 256, 0, stream>>>(att, P, T);

    // y = P v: per batch [2048,2048] x [768,2048]^T, K truncated causally, longest-first
    k_gemm<2><<<dim3(6, 16, B), 256, 0, stream>>>(P, vT, T, T, T,
        (size_t)T * T, (size_t)C * T, (size_t)T * C, y, C, 0, nullptr, 1.f,
        nullptr, nullptr, nullptr);

    // Wh^T after PV so it can overwrite att/P scratch
    k_transpose_f32_bf16<<<dim3(Vp / 32, 24), 256, 0, stream>>>(Wh, whT, C, V, Vp);

    k_layernorm<<<dim3(B * T), 256, 0, stream>>>(y, ln_g, ln_b, yn);

    // logits: [8192,768] x [50432,768]^T -> fp32 d_out; 256x128 tile, 2 blocks/CU
    // grid: bm fastest (x=32) so co-resident blocks share a B-panel
    k_gemm_head<<<dim3(32, Vp / 128), 512, 0, stream>>>(yn, whT, out, bh, V, V);
}